// Round 2
// 423.050 us; speedup vs baseline: 1.2789x; 1.2789x over previous
//
#include <hip/hip_runtime.h>
#include <hip/hip_bf16.h>
#include <hip/hip_fp16.h>

#define OC_N     2048
#define IC_N     2048
#define RC       6144      // rows = OC_N*3, cols = IC_N*3
#define OCSTRIDE 18432     // IC_N*9 floats per oc slice
#define UNSCALE  0.0000152587890625f   // 2^-16 cancels the fp8 256x encode scale per iter

typedef float v2f __attribute__((ext_vector_type(2)));

__device__ __forceinline__ float wave_reduce(float x) {
#pragma unroll
    for (int off = 32; off > 0; off >>= 1) x += __shfl_down(x, off, 64);
    return x;
}

// ---------------------------------------------------------------------------
// Wq[r][c] = fp8_e4m3(256 * conv[oc][ic][hh][ww]), r=oc*3+hh, c=ic*3+ww.
// Thread writes 8 consecutive fp8 (8B store, coalesced). 18432 blocks.
__global__ __launch_bounds__(256) void convert_q_kernel(
    const float* __restrict__ conv, unsigned char* __restrict__ Wq)
{
    const int t  = blockIdx.x * 256 + threadIdx.x;
    const int o8 = t * 8;                       // < 2^26, fits int
    const int r  = o8 / RC;
    const int c0 = o8 % RC;
    const int oc = r / 3, hh = r % 3;
    const float* base = conv + (size_t)oc * OCSTRIDE + hh * 3;
    float f[8];
#pragma unroll
    for (int e = 0; e < 8; ++e) {
        const int c  = c0 + e;
        const int ic = c / 3, ww = c - 3 * ic;
        f[e] = base[ic * 9 + ww] * 256.0f;
    }
    int lo = __builtin_amdgcn_cvt_pk_fp8_f32(f[0], f[1], 0, false);
    lo     = __builtin_amdgcn_cvt_pk_fp8_f32(f[2], f[3], lo, true);
    int hi = __builtin_amdgcn_cvt_pk_fp8_f32(f[4], f[5], 0, false);
    hi     = __builtin_amdgcn_cvt_pk_fp8_f32(f[6], f[7], hi, true);
    *reinterpret_cast<uint2*>(Wq + o8) = make_uint2((unsigned)lo, (unsigned)hi);
}

// ---------------------------------------------------------------------------
// WqT[c][r] = Wq[r][c]  — 64x64 byte tiles via LDS. Grid (96, 96), 256 thr.
// LDS row stride 68 B (odd word count) keeps accesses to <=2-way conflicts.
__global__ __launch_bounds__(256) void transpose_q_kernel(
    const unsigned char* __restrict__ Wq, unsigned char* __restrict__ WqT)
{
    __shared__ unsigned char tile[64][68];
    const int tid = threadIdx.x;
    const int tr  = blockIdx.x;          // row tile of Wq
    const int tc  = blockIdx.y;          // col tile of Wq

    // load: thread -> one uint4 (row r, 16 cols)
    const int r  = tid >> 2;
    const int cq = (tid & 3) * 16;
    const uint4 w = *reinterpret_cast<const uint4*>(
        Wq + (size_t)(tr * 64 + r) * RC + tc * 64 + cq);
    *reinterpret_cast<unsigned int*>(&tile[r][cq +  0]) = w.x;
    *reinterpret_cast<unsigned int*>(&tile[r][cq +  4]) = w.y;
    *reinterpret_cast<unsigned int*>(&tile[r][cq +  8]) = w.z;
    *reinterpret_cast<unsigned int*>(&tile[r][cq + 12]) = w.w;
    __syncthreads();

    // gather transposed: output row orow (= Wq col), 16 output cols
    const int orow = tid >> 2;
    const int ocq  = (tid & 3) * 16;
    unsigned int u32s[4];
#pragma unroll
    for (int wi = 0; wi < 4; ++wi) {
        const int ro = ocq + 4 * wi;
        u32s[wi] =  (unsigned int)tile[ro + 0][orow]
                 | ((unsigned int)tile[ro + 1][orow] << 8)
                 | ((unsigned int)tile[ro + 2][orow] << 16)
                 | ((unsigned int)tile[ro + 3][orow] << 24);
    }
    uint4 o = make_uint4(u32s[0], u32s[1], u32s[2], u32s[3]);
    *reinterpret_cast<uint4*>(WqT + (size_t)(tc * 64 + orow) * RC + tr * 64 + ocq) = o;
}

// ---------------------------------------------------------------------------
// 16-element fp8 dot: w holds 16 fp8, a..d hold the 16 matching f32 x-values.
__device__ __forceinline__ float dot16(uint4 w, float4 a, float4 b, float4 c, float4 d) {
    float acc = 0.f;
    v2f f;
    f = __builtin_amdgcn_cvt_pk_f32_fp8(w.x, false); acc += f.x * a.x + f.y * a.y;
    f = __builtin_amdgcn_cvt_pk_f32_fp8(w.x, true);  acc += f.x * a.z + f.y * a.w;
    f = __builtin_amdgcn_cvt_pk_f32_fp8(w.y, false); acc += f.x * b.x + f.y * b.y;
    f = __builtin_amdgcn_cvt_pk_f32_fp8(w.y, true);  acc += f.x * b.z + f.y * b.w;
    f = __builtin_amdgcn_cvt_pk_f32_fp8(w.z, false); acc += f.x * c.x + f.y * c.y;
    f = __builtin_amdgcn_cvt_pk_f32_fp8(w.z, true);  acc += f.x * c.z + f.y * c.w;
    f = __builtin_amdgcn_cvt_pk_f32_fp8(w.w, false); acc += f.x * d.x + f.y * d.y;
    f = __builtin_amdgcn_cvt_pk_f32_fp8(w.w, true);  acc += f.x * d.z + f.y * d.w;
    return acc;
}

// ---------------------------------------------------------------------------
// y[r] = scale * sum_c W[r][c] * x[c].   768 blocks x 256 thr (3/CU exact).
// Block = 8 rows, wave = 2 rows, uint4 (16B) weight loads.
// x staged in LDS padded (+1 float4 slot per 4): lane byte-stride 80 -> bank
// stride 20; 20*l mod 32 partitions all 32 banks over 8 lanes -> ds_read_b128
// is conflict-free.
__global__ __launch_bounds__(256) void matvec_q_kernel(
    const unsigned char* __restrict__ W, const float* __restrict__ x,
    float* __restrict__ y, float scale)
{
    __shared__ float x_lds[7680];                 // 6144 + 1536 pad floats
    float4* x4 = reinterpret_cast<float4*>(x_lds);

    const int tid  = threadIdx.x;
    const int lane = tid & 63;
    const int wid  = tid >> 6;

    const float4* s4 = reinterpret_cast<const float4*>(x);
#pragma unroll
    for (int k = 0; k < 6; ++k) {
        const int g = tid + 256 * k;              // logical float4 index
        x4[g + (g >> 2)] = s4[g];                 // padded slot
    }
    __syncthreads();

    const int rbase = blockIdx.x * 8 + wid * 2;
    const unsigned char* w0 = W + (size_t)rbase * RC;
    float acc0 = 0.f, acc1 = 0.f;
#pragma unroll
    for (int i = 0; i < 6; ++i) {
        const int slot = i * 320 + lane * 5;      // padded float4 slot
        const float4 a = x4[slot + 0];
        const float4 b = x4[slot + 1];
        const float4 c = x4[slot + 2];
        const float4 d = x4[slot + 3];
        const uint4 wA = *reinterpret_cast<const uint4*>(w0 +      i * 1024 + lane * 16);
        const uint4 wB = *reinterpret_cast<const uint4*>(w0 + RC + i * 1024 + lane * 16);
        acc0 += dot16(wA, a, b, c, d);
        acc1 += dot16(wB, a, b, c, d);
    }
    acc0 = wave_reduce(acc0);
    acc1 = wave_reduce(acc1);
    if (lane == 0) { y[rbase] = acc0 * scale; y[rbase + 1] = acc1 * scale; }
}

// ---------------------------------------------------------------------------
// Final fp32 pass on ORIGINAL conv: t = W * (u/||u||). One block per oc.
__global__ __launch_bounds__(256) void vstep_kernel(
    const float* __restrict__ conv, const float* __restrict__ u,
    float* __restrict__ v_out)
{
    __shared__ float u_lds[RC];
    __shared__ float sred[8];
    __shared__ float sred3[12];
    __shared__ float sbcast;

    const int tid  = threadIdx.x;
    const int oc   = blockIdx.x;
    const int lane = tid & 63;
    const int wid  = tid >> 6;

    float sq = 0.f;
    const float4* u4  = reinterpret_cast<const float4*>(u);
    float4*       ul4 = reinterpret_cast<float4*>(u_lds);
#pragma unroll
    for (int k = 0; k < 6; ++k) {
        float4 q = u4[tid + 256 * k];
        ul4[tid + 256 * k] = q;
        sq += q.x * q.x + q.y * q.y + q.z * q.z + q.w * q.w;
    }
    float wsum = wave_reduce(sq);
    if (lane == 0) sred[wid] = wsum;
    __syncthreads();
    if (tid == 0) sbcast = rsqrtf(sred[0] + sred[1] + sred[2] + sred[3]);
    __syncthreads();
    const float scale = sbcast;

    float acc0 = 0.f, acc1 = 0.f, acc2 = 0.f;
    const float* base = conv + (size_t)oc * OCSTRIDE;
#pragma unroll
    for (int gi = 0; gi < 2; ++gi) {
        const int g = tid + 256 * gi;
        const float4* p4  = reinterpret_cast<const float4*>(base + g * 36);
        const float4* q12 = reinterpret_cast<const float4*>(u_lds + 12 * g);
        float uv[12];
#pragma unroll
        for (int k = 0; k < 3; ++k) {
            float4 q = q12[k];
            uv[4 * k] = q.x; uv[4 * k + 1] = q.y; uv[4 * k + 2] = q.z; uv[4 * k + 3] = q.w;
        }
#pragma unroll
        for (int j = 0; j < 9; ++j) {
            float4 q = p4[j];
            float el[4] = {q.x, q.y, q.z, q.w};
#pragma unroll
            for (int e = 0; e < 4; ++e) {
                const int m   = 4 * j + e;
                const int icl = m / 9;
                const int rem = m - 9 * icl;
                const int hh  = rem / 3;
                const int ww  = rem - 3 * hh;
                const float pv = el[e] * uv[icl * 3 + ww];
                if (hh == 0) acc0 += pv;
                else if (hh == 1) acc1 += pv;
                else acc2 += pv;
            }
        }
    }
    acc0 = wave_reduce(acc0);
    acc1 = wave_reduce(acc1);
    acc2 = wave_reduce(acc2);
    if (lane == 0) { sred3[wid] = acc0; sred3[4 + wid] = acc1; sred3[8 + wid] = acc2; }
    __syncthreads();
    if (tid < 3) {
        const float s = sred3[tid * 4 + 0] + sred3[tid * 4 + 1] +
                        sred3[tid * 4 + 2] + sred3[tid * 4 + 3];
        v_out[oc * 3 + tid] = scale * s;
    }
}

// out = 3 * dot(v,t) / ||v||   (v unnormalized iterate, t = W u_hat)
__global__ __launch_bounds__(256) void final_kernel(
    const float* __restrict__ v, const float* __restrict__ t,
    float* __restrict__ out)
{
    __shared__ float ssq[4];
    __shared__ float sdot[4];
    const int tid  = threadIdx.x;
    const int lane = tid & 63;
    const int wid  = tid >> 6;
    float sq = 0.f, dot = 0.f;
#pragma unroll
    for (int k = 0; k < 24; ++k) {
        float x = v[tid + 256 * k];
        float y = t[tid + 256 * k];
        sq  += x * x;
        dot += x * y;
    }
    sq  = wave_reduce(sq);
    dot = wave_reduce(dot);
    if (lane == 0) { ssq[wid] = sq; sdot[wid] = dot; }
    __syncthreads();
    if (tid == 0) {
        const float sqt  = ssq[0] + ssq[1] + ssq[2] + ssq[3];
        const float dott = sdot[0] + sdot[1] + sdot[2] + sdot[3];
        out[0] = 3.0f * dott * rsqrtf(sqt);
    }
}

extern "C" void kernel_launch(void* const* d_in, const int* in_sizes, int n_in,
                              void* d_out, int out_size, void* d_ws, size_t ws_size,
                              hipStream_t stream)
{
    const float* conv = (const float*)d_in[0];   // [2048,2048,3,3] fp32
    const float* u_in = (const float*)d_in[1];   // [1,6144] fp32, unit norm
    float* out = (float*)d_out;

    // ws layout: Wq fp8[6144^2] | WqT fp8[6144^2] | v_vec[6144] | u_vec[6144]
    //            | t_vec[6144] floats
    const size_t WQ_BYTES = (size_t)RC * RC;                     // 37.75 MB
    const size_t needed = 2 * WQ_BYTES + (size_t)3 * RC * sizeof(float);
    if (ws_size < needed) return;

    unsigned char* Wq  = (unsigned char*)d_ws;
    unsigned char* WqT = Wq + WQ_BYTES;
    float* v_vec = (float*)(WqT + WQ_BYTES);
    float* u_vec = v_vec + RC;
    float* t_vec = u_vec + RC;

    convert_q_kernel<<<RC * RC / 8 / 256, 256, 0, stream>>>(conv, Wq);
    transpose_q_kernel<<<dim3(RC / 64, RC / 64), 256, 0, stream>>>(Wq, WqT);

    for (int i = 0; i < 10; ++i) {
        matvec_q_kernel<<<RC / 8, 256, 0, stream>>>(
            Wq, (i == 0) ? u_in : u_vec, v_vec, 1.0f);
        matvec_q_kernel<<<RC / 8, 256, 0, stream>>>(
            WqT, v_vec, u_vec, UNSCALE);
    }

    // sigma in full fp32 from original data
    vstep_kernel<<<OC_N, 256, 0, stream>>>(conv, u_vec, t_vec);
    final_kernel<<<1, 256, 0, stream>>>(v_vec, t_vec, out);
}